// Round 12
// baseline (230.394 us; speedup 1.0000x reference)
//
#include <hip/hip_runtime.h>
#include <stdint.h>

#define M_DIM 8192
#define N_DIM 4096
#define K_DIM 4096
#define QMAXF 127.0f
#define QDIVF 127.5f

typedef int v4i __attribute__((ext_vector_type(4)));

// ---------------- address-space helpers for global_load_lds ----------------
typedef __attribute__((address_space(3))) void lds_void_t;
typedef __attribute__((address_space(1))) const void glb_void_t;

static __device__ __forceinline__ void load_lds16(const void* g, void* l) {
    __builtin_amdgcn_global_load_lds((glb_void_t*)g, (lds_void_t*)l, 16, 0, 0);
}

// ---- kernel 1: fused prep pass 1: [row absmax+quant lhs] ∥ [col absmax rhs] ----
// blocks 0..8191: one lhs row each. blocks 8192..8703: rhs col-absmax partials
// (128 rows per block -> 2M atomics total, half of R10).
__global__ __launch_bounds__(256) void prep1_kernel(
        const float* __restrict__ lhs, const float* __restrict__ rhs,
        float* __restrict__ sL, unsigned* __restrict__ bits,
        int8_t* __restrict__ ql) {
    const int t = threadIdx.x;
    if (blockIdx.x < M_DIM) {
        const int row = blockIdx.x;
        const float4* rp = (const float4*)(lhs + (size_t)row * K_DIM);
        float4 v[4];
        float m = 0.0f;
#pragma unroll
        for (int i = 0; i < 4; ++i) {
            v[i] = rp[t + i * 256];
            m = fmaxf(m, fmaxf(fmaxf(fabsf(v[i].x), fabsf(v[i].y)),
                               fmaxf(fabsf(v[i].z), fabsf(v[i].w))));
        }
#pragma unroll
        for (int off = 32; off; off >>= 1) m = fmaxf(m, __shfl_down(m, off, 64));
        __shared__ float wmax[4];
        if ((t & 63) == 0) wmax[t >> 6] = m;
        __syncthreads();
        const float mm = fmaxf(fmaxf(wmax[0], wmax[1]), fmaxf(wmax[2], wmax[3]));
        float s = mm / QDIVF;
        s = (s == 0.0f) ? 1.0f : s;
        if (t == 0) sL[row] = s;
        unsigned* qo = (unsigned*)ql + (size_t)row * 1024;
#pragma unroll
        for (int i = 0; i < 4; ++i) {
            int q0 = (int)fminf(fmaxf(rintf(v[i].x / s), -QMAXF), QMAXF);
            int q1 = (int)fminf(fmaxf(rintf(v[i].y / s), -QMAXF), QMAXF);
            int q2 = (int)fminf(fmaxf(rintf(v[i].z / s), -QMAXF), QMAXF);
            int q3 = (int)fminf(fmaxf(rintf(v[i].w / s), -QMAXF), QMAXF);
            qo[t + i * 256] = (q0 & 255) | ((q1 & 255) << 8) | ((q2 & 255) << 16)
                            | ((unsigned)(q3 & 255) << 24);
        }
    } else {
        const int cb = blockIdx.x - M_DIM;     // 0..511
        const int col = (cb & 15) * 256 + t;
        const int r0 = (cb >> 4) * 128;        // 32 row-groups of 128
        float m = 0.0f;
#pragma unroll 4
        for (int r = 0; r < 128; ++r)
            m = fmaxf(m, fabsf(rhs[(size_t)(r0 + r) * N_DIM + col]));
        atomicMax(&bits[col], __float_as_uint(m));   // abs >= 0: bit order == float order
    }
}

// -- kernel 2: quantize + transpose rhs -> q_rT [N][K]; also materialize sR --
__global__ __launch_bounds__(256) void quant_rhs_t_kernel(
        const float* __restrict__ rhs, const unsigned* __restrict__ bits,
        float* __restrict__ sR, int8_t* __restrict__ qbT) {
    __shared__ __align__(16) int8_t lt[64][80];
    const int n0 = blockIdx.x * 64;
    const int k0 = blockIdx.y * 64;
    const int t = threadIdx.x;
    const int nloc = t & 63;
    const int kq = (t >> 6) * 16;
    float s = __uint_as_float(bits[n0 + nloc]) / QDIVF;
    s = (s == 0.0f) ? 1.0f : s;
    if (blockIdx.y == 0 && t < 64) {
        float ss = __uint_as_float(bits[n0 + t]) / QDIVF;
        sR[n0 + t] = (ss == 0.0f) ? 1.0f : ss;
    }
#pragma unroll
    for (int i = 0; i < 4; ++i) {
        unsigned pack = 0;
#pragma unroll
        for (int j = 0; j < 4; ++j) {
            int kk = kq + i * 4 + j;
            float x = rhs[(size_t)(k0 + kk) * N_DIM + n0 + nloc];
            int q = (int)fminf(fmaxf(rintf(x / s), -QMAXF), QMAXF);
            pack |= (unsigned)(q & 255) << (8 * j);
        }
        *(unsigned*)&lt[nloc][kq + i * 4] = pack;
    }
    __syncthreads();
    const int nn = t >> 2, ch = t & 3;
    v4i val = *(const v4i*)&lt[nn][ch * 16];
    *(v4i*)&qbT[(size_t)(n0 + nn) * K_DIM + k0 + ch * 16] = val;
}

// ====== kernel 3: int8 GEMM — R5's best-measured structure (148.4 us) ======
// 256x256 tile, BK=64, ring-4, 1 barrier/tile, reg-dbuf'd ks-clusters,
// mfma_i32_16x16x64_i8, counted VMCNT(4). Only change vs R5: the
// R7-validated 2D XCD partition (FETCH 274->98 MB).
// Invariant: at the barrier ending tile KT, tiles <= KT+2 are landed in LDS
// for ALL waves (VMCNT(4) before the barrier drains KT+2). Inside tile KT:
// read tile KT ks1 at top (landed 2 bars ago) and tile KT+1 ks0 between MFMA
// clusters (landed at last bar). WAR: stage of KT+3 overwrites buf of KT-1,
// whose reads lgkm-completed before the previous barrier.

#define BAR() do { asm volatile("" ::: "memory");          \
                   __builtin_amdgcn_s_barrier();           \
                   asm volatile("" ::: "memory"); } while (0)

#define VMCNT(N) asm volatile("s_waitcnt vmcnt(%0)" :: "n"(N) : "memory")

#define STAGE_A(h, kt, bq) \
    load_lds16(gA0 + (size_t)((h) * 128) * K_DIM + (size_t)(kt) * 64, \
               lds + (bq) * 16384 + (h) * 8192 + sdst)
#define STAGE_B(h, kt, bq) \
    load_lds16(gB0 + (size_t)((h) * 128) * K_DIM + (size_t)(kt) * 64, \
               lds + 65536 + (bq) * 16384 + (h) * 8192 + sdst)

#define RD_A(BUF, MM) (*(const v4i*)(lds + (BUF) * 16384 + aoff[MM]))
#define RD_B(BUF, NN) (*(const v4i*)(lds + (BUF) * 16384 + boff[NN]))

// TILE: BUF = KT & 3, P = KT & 1 (both compile-time). S: stage KT+3.
// RDN: read tile KT+1 fragments. VM: counted vmcnt before barrier.
#define TILE(KT, BUF, P, S, VM, RDN) do {                                       \
    _Pragma("unroll") for (int nn = 0; nn < 4; ++nn)                            \
        bfII[nn] = RD_B(BUF, 4 + nn);                                           \
    if (S) { STAGE_A(0, (KT) + 3, ((BUF) + 3) & 3);                             \
             STAGE_A(1, (KT) + 3, ((BUF) + 3) & 3);                             \
             STAGE_B(0, (KT) + 3, ((BUF) + 3) & 3);                             \
             STAGE_B(1, (KT) + 3, ((BUF) + 3) & 3); }                           \
    __builtin_amdgcn_s_setprio(1);                                              \
    _Pragma("unroll") for (int mm = 0; mm < 4; ++mm)                            \
    _Pragma("unroll") for (int nn = 0; nn < 4; ++nn)                            \
        acc[mm][nn] = __builtin_amdgcn_mfma_i32_16x16x64_i8(                    \
            af[P][mm], bfI[P][nn], acc[mm][nn], 0, 0, 0);                       \
    __builtin_amdgcn_s_setprio(0);                                              \
    if (RDN) {                                                                  \
        _Pragma("unroll") for (int mm = 0; mm < 4; ++mm)                        \
            af[(P) ^ 1][mm] = RD_A(((BUF) + 1) & 3, mm);                        \
        _Pragma("unroll") for (int nn = 0; nn < 4; ++nn)                        \
            bfI[(P) ^ 1][nn] = RD_B(((BUF) + 1) & 3, nn);                       \
    }                                                                           \
    __builtin_amdgcn_s_setprio(1);                                              \
    _Pragma("unroll") for (int mm = 0; mm < 4; ++mm)                            \
    _Pragma("unroll") for (int nn = 0; nn < 4; ++nn)                            \
        acc[mm][4 + nn] = __builtin_amdgcn_mfma_i32_16x16x64_i8(                \
            af[P][mm], bfII[nn], acc[mm][4 + nn], 0, 0, 0);                     \
    __builtin_amdgcn_s_setprio(0);                                              \
    VMCNT(VM);                                                                  \
    BAR();                                                                      \
} while (0)

__global__ __launch_bounds__(512, 2) void gemm_i8_kernel(
        const int8_t* __restrict__ qa, const int8_t* __restrict__ qbT,
        const float* __restrict__ sL, const float* __restrict__ sR,
        float* __restrict__ out) {
    __shared__ __align__(16) int8_t lds[131072];

    const int t = threadIdx.x;
    const int wave = t >> 6;
    const int lane = t & 63;

    // 2D XCD partition (R7-validated): each XCD owns 8mt x 8nt. Bijective.
    const int bid = blockIdx.x;
    const int xcd = bid & 7;
    const int idx = bid >> 3;                    // 0..63
    const int mt = (xcd >> 1) * 8 + (idx & 7);   // 0..31
    const int nt = (xcd & 1) * 8 + (idx >> 3);   // 0..15
    const int brow = mt * 256;
    const int bcol = nt * 256;

    const int wm = (wave >> 1) * 64;     // 4 M-groups of 64 rows
    const int wn = (wave & 1) * 128;     // 2 N-groups of 128 cols

    // fragment read byte-offsets (swizzled; 64B rows) — R5-validated
    int aoff[4], boff[8];
#pragma unroll
    for (int m = 0; m < 4; ++m) {
        int row = wm + m * 16 + (lane & 15);
        aoff[m] = row * 64 + (((lane >> 4) ^ ((row >> 1) & 3)) * 16);
    }
#pragma unroll
    for (int n = 0; n < 8; ++n) {
        int row = wn + n * 16 + (lane & 15);
        boff[n] = 65536 + row * 64 + (((lane >> 4) ^ ((row >> 1) & 3)) * 16);
    }

    v4i acc[4][8];
#pragma unroll
    for (int m = 0; m < 4; ++m)
#pragma unroll
        for (int n = 0; n < 8; ++n) acc[m][n] = (v4i){0, 0, 0, 0};

    // staging: thread t covers bytes [t*16, t*16+16) of an 8KB half-tile;
    // source chunk pre-swizzled so linear LDS holds the swizzled layout.
    const int srow = t >> 2;                                  // 0..127
    const int lcA = (t & 3) ^ ((srow >> 1) & 3);
    const int8_t* gA0 = qa  + (size_t)(brow + srow) * K_DIM + lcA * 16;
    const int8_t* gB0 = qbT + (size_t)(bcol + srow) * K_DIM + lcA * 16;
    const int sdst = t * 16;

    v4i af[2][4], bfI[2][4], bfII[4];

    // prologue: stage tiles 0,1,2 (tile-monotone); drain T0,T1 for ALL waves
    // (VMCNT then BARRIER) BEFORE any LDS read -> no cross-wave race.
    STAGE_A(0, 0, 0); STAGE_A(1, 0, 0); STAGE_B(0, 0, 0); STAGE_B(1, 0, 0);
    STAGE_A(0, 1, 1); STAGE_A(1, 1, 1); STAGE_B(0, 1, 1); STAGE_B(1, 1, 1);
    STAGE_A(0, 2, 2); STAGE_A(1, 2, 2); STAGE_B(0, 2, 2); STAGE_B(1, 2, 2);
    VMCNT(4);
    BAR();
#pragma unroll
    for (int mm = 0; mm < 4; ++mm) af[0][mm] = RD_A(0, mm);
#pragma unroll
    for (int nn = 0; nn < 4; ++nn) bfI[0][nn] = RD_B(0, nn);

    for (int kt = 0; kt < 60; kt += 4) {
        TILE(kt + 0, 0, 0, 1, 4, 1);
        TILE(kt + 1, 1, 1, 1, 4, 1);
        TILE(kt + 2, 2, 0, 1, 4, 1);
        TILE(kt + 3, 3, 1, 1, 4, 1);
    }
    TILE(60, 0, 0, 1, 4, 1);   // stages T63; drains T62
    TILE(61, 1, 1, 0, 0, 1);   // drains T63 before barrier
    TILE(62, 2, 0, 0, 0, 1);
    TILE(63, 3, 1, 0, 0, 0);

    // Epilogue (validated): 16x16 C/D: col = lane&15, row = (lane>>4)*4 + reg
    const int r4 = (lane >> 4) * 4;
    const int cc = lane & 15;
#pragma unroll
    for (int m = 0; m < 4; ++m) {
        const int grow0 = brow + wm + m * 16 + r4;
        const float s0 = sL[grow0 + 0];
        const float s1 = sL[grow0 + 1];
        const float s2 = sL[grow0 + 2];
        const float s3 = sL[grow0 + 3];
#pragma unroll
        for (int n = 0; n < 8; ++n) {
            const int gcol = bcol + wn + n * 16 + cc;
            const float sc = sR[gcol];
            float* o = out + (size_t)grow0 * N_DIM + gcol;
            o[0 * N_DIM] = (float)acc[m][n][0] * s0 * sc;
            o[1 * N_DIM] = (float)acc[m][n][1] * s1 * sc;
            o[2 * N_DIM] = (float)acc[m][n][2] * s2 * sc;
            o[3 * N_DIM] = (float)acc[m][n][3] * s3 * sc;
        }
    }
}

// ---------------- launch ----------------
extern "C" void kernel_launch(void* const* d_in, const int* in_sizes, int n_in,
                              void* d_out, int out_size, void* d_ws, size_t ws_size,
                              hipStream_t stream) {
    const float* lhs = (const float*)d_in[0];
    const float* rhs = (const float*)d_in[1];
    float* out = (float*)d_out;

    uint8_t* ws = (uint8_t*)d_ws;
    int8_t* ql    = (int8_t*)ws;                               // 33,554,432 B
    int8_t* qbT   = (int8_t*)(ws + 33554432);                  // 16,777,216 B
    float* sL     = (float*)(ws + 50331648);                   // 32,768 B
    float* sR     = (float*)(ws + 50331648 + 32768);           // 16,384 B
    unsigned* bits = (unsigned*)(ws + 50331648 + 32768 + 16384); // 16,384 B

    hipMemsetAsync(bits, 0, N_DIM * sizeof(unsigned), stream);

    prep1_kernel<<<M_DIM + 512, 256, 0, stream>>>(lhs, rhs, sL, bits, ql);
    quant_rhs_t_kernel<<<dim3(N_DIM / 64, K_DIM / 64), 256, 0, stream>>>(
        rhs, bits, sR, qbT);
    gemm_i8_kernel<<<dim3((M_DIM / 256) * (N_DIM / 256)), 512, 0, stream>>>(
        ql, qbT, sL, sR, out);
}

// Round 13
// 211.577 us; speedup vs baseline: 1.0889x; 1.0889x over previous
//
#include <hip/hip_runtime.h>
#include <stdint.h>

#define M_DIM 8192
#define N_DIM 4096
#define K_DIM 4096
#define QMAXF 127.0f
#define QDIVF 127.5f

typedef int v4i __attribute__((ext_vector_type(4)));

// ---------------- address-space helpers for global_load_lds ----------------
typedef __attribute__((address_space(3))) void lds_void_t;
typedef __attribute__((address_space(1))) const void glb_void_t;

static __device__ __forceinline__ void load_lds16(const void* g, void* l) {
    __builtin_amdgcn_global_load_lds((glb_void_t*)g, (lds_void_t*)l, 16, 0, 0);
}

// ---- kernel 1: fused prep pass 1: [row absmax+quant lhs] ∥ [col absmax rhs] ----
// blocks 0..8191: one lhs row each (read once, quantize in-reg).
// blocks 8192..9215: rhs col-absmax partials, 64 rows/block (R10-validated:
// 1024 blocks keeps the latency-exposed column walk TLP-saturated).
__global__ __launch_bounds__(256) void prep1_kernel(
        const float* __restrict__ lhs, const float* __restrict__ rhs,
        float* __restrict__ sL, unsigned* __restrict__ bits,
        int8_t* __restrict__ ql) {
    const int t = threadIdx.x;
    if (blockIdx.x < M_DIM) {
        const int row = blockIdx.x;
        const float4* rp = (const float4*)(lhs + (size_t)row * K_DIM);
        float4 v[4];
        float m = 0.0f;
#pragma unroll
        for (int i = 0; i < 4; ++i) {
            v[i] = rp[t + i * 256];
            m = fmaxf(m, fmaxf(fmaxf(fabsf(v[i].x), fabsf(v[i].y)),
                               fmaxf(fabsf(v[i].z), fabsf(v[i].w))));
        }
#pragma unroll
        for (int off = 32; off; off >>= 1) m = fmaxf(m, __shfl_down(m, off, 64));
        __shared__ float wmax[4];
        if ((t & 63) == 0) wmax[t >> 6] = m;
        __syncthreads();
        const float mm = fmaxf(fmaxf(wmax[0], wmax[1]), fmaxf(wmax[2], wmax[3]));
        float s = mm / QDIVF;
        s = (s == 0.0f) ? 1.0f : s;
        if (t == 0) sL[row] = s;
        unsigned* qo = (unsigned*)ql + (size_t)row * 1024;
#pragma unroll
        for (int i = 0; i < 4; ++i) {
            int q0 = (int)fminf(fmaxf(rintf(v[i].x / s), -QMAXF), QMAXF);
            int q1 = (int)fminf(fmaxf(rintf(v[i].y / s), -QMAXF), QMAXF);
            int q2 = (int)fminf(fmaxf(rintf(v[i].z / s), -QMAXF), QMAXF);
            int q3 = (int)fminf(fmaxf(rintf(v[i].w / s), -QMAXF), QMAXF);
            qo[t + i * 256] = (q0 & 255) | ((q1 & 255) << 8) | ((q2 & 255) << 16)
                            | ((unsigned)(q3 & 255) << 24);
        }
    } else {
        const int cb = blockIdx.x - M_DIM;     // 0..1023
        const int col = (cb & 15) * 256 + t;
        const int r0 = (cb >> 4) * 64;
        float m = 0.0f;
#pragma unroll 4
        for (int r = 0; r < 64; ++r)
            m = fmaxf(m, fabsf(rhs[(size_t)(r0 + r) * N_DIM + col]));
        atomicMax(&bits[col], __float_as_uint(m));   // abs >= 0: bit order == float order
    }
}

// -- kernel 2: quantize + transpose rhs -> q_rT [N][K]; also materialize sR --
__global__ __launch_bounds__(256) void quant_rhs_t_kernel(
        const float* __restrict__ rhs, const unsigned* __restrict__ bits,
        float* __restrict__ sR, int8_t* __restrict__ qbT) {
    __shared__ __align__(16) int8_t lt[64][80];
    const int n0 = blockIdx.x * 64;
    const int k0 = blockIdx.y * 64;
    const int t = threadIdx.x;
    const int nloc = t & 63;
    const int kq = (t >> 6) * 16;
    float s = __uint_as_float(bits[n0 + nloc]) / QDIVF;
    s = (s == 0.0f) ? 1.0f : s;
    if (blockIdx.y == 0 && t < 64) {
        float ss = __uint_as_float(bits[n0 + t]) / QDIVF;
        sR[n0 + t] = (ss == 0.0f) ? 1.0f : ss;
    }
#pragma unroll
    for (int i = 0; i < 4; ++i) {
        unsigned pack = 0;
#pragma unroll
        for (int j = 0; j < 4; ++j) {
            int kk = kq + i * 4 + j;
            float x = rhs[(size_t)(k0 + kk) * N_DIM + n0 + nloc];
            int q = (int)fminf(fmaxf(rintf(x / s), -QMAXF), QMAXF);
            pack |= (unsigned)(q & 255) << (8 * j);
        }
        *(unsigned*)&lt[nloc][kq + i * 4] = pack;
    }
    __syncthreads();
    const int nn = t >> 2, ch = t & 3;
    v4i val = *(const v4i*)&lt[nn][ch * 16];
    *(v4i*)&qbT[(size_t)(n0 + nn) * K_DIM + k0 + ch * 16] = val;
}

// ====== kernel 3: int8 GEMM — best-measured (R12: 143.6 us, MfmaUtil 44) ======
// 256x256 tile, BK=64, ring-4, 1 barrier/tile, reg-dbuf'd ks-clusters,
// mfma_i32_16x16x64_i8, counted VMCNT(4), 2D XCD partition. BYTE-IDENTICAL
// to R12's GEMM.
// Invariant: at the barrier ending tile KT, tiles <= KT+2 are landed in LDS
// for ALL waves (VMCNT(4) before the barrier drains KT+2). Inside tile KT:
// read tile KT ks1 at top (landed 2 bars ago) and tile KT+1 ks0 between MFMA
// clusters (landed at last bar). WAR: stage of KT+3 overwrites buf of KT-1,
// whose reads lgkm-completed before the previous barrier.

#define BAR() do { asm volatile("" ::: "memory");          \
                   __builtin_amdgcn_s_barrier();           \
                   asm volatile("" ::: "memory"); } while (0)

#define VMCNT(N) asm volatile("s_waitcnt vmcnt(%0)" :: "n"(N) : "memory")

#define STAGE_A(h, kt, bq) \
    load_lds16(gA0 + (size_t)((h) * 128) * K_DIM + (size_t)(kt) * 64, \
               lds + (bq) * 16384 + (h) * 8192 + sdst)
#define STAGE_B(h, kt, bq) \
    load_lds16(gB0 + (size_t)((h) * 128) * K_DIM + (size_t)(kt) * 64, \
               lds + 65536 + (bq) * 16384 + (h) * 8192 + sdst)

#define RD_A(BUF, MM) (*(const v4i*)(lds + (BUF) * 16384 + aoff[MM]))
#define RD_B(BUF, NN) (*(const v4i*)(lds + (BUF) * 16384 + boff[NN]))

// TILE: BUF = KT & 3, P = KT & 1 (both compile-time). S: stage KT+3.
// RDN: read tile KT+1 fragments. VM: counted vmcnt before barrier.
#define TILE(KT, BUF, P, S, VM, RDN) do {                                       \
    _Pragma("unroll") for (int nn = 0; nn < 4; ++nn)                            \
        bfII[nn] = RD_B(BUF, 4 + nn);                                           \
    if (S) { STAGE_A(0, (KT) + 3, ((BUF) + 3) & 3);                             \
             STAGE_A(1, (KT) + 3, ((BUF) + 3) & 3);                             \
             STAGE_B(0, (KT) + 3, ((BUF) + 3) & 3);                             \
             STAGE_B(1, (KT) + 3, ((BUF) + 3) & 3); }                           \
    __builtin_amdgcn_s_setprio(1);                                              \
    _Pragma("unroll") for (int mm = 0; mm < 4; ++mm)                            \
    _Pragma("unroll") for (int nn = 0; nn < 4; ++nn)                            \
        acc[mm][nn] = __builtin_amdgcn_mfma_i32_16x16x64_i8(                    \
            af[P][mm], bfI[P][nn], acc[mm][nn], 0, 0, 0);                       \
    __builtin_amdgcn_s_setprio(0);                                              \
    if (RDN) {                                                                  \
        _Pragma("unroll") for (int mm = 0; mm < 4; ++mm)                        \
            af[(P) ^ 1][mm] = RD_A(((BUF) + 1) & 3, mm);                        \
        _Pragma("unroll") for (int nn = 0; nn < 4; ++nn)                        \
            bfI[(P) ^ 1][nn] = RD_B(((BUF) + 1) & 3, nn);                       \
    }                                                                           \
    __builtin_amdgcn_s_setprio(1);                                              \
    _Pragma("unroll") for (int mm = 0; mm < 4; ++mm)                            \
    _Pragma("unroll") for (int nn = 0; nn < 4; ++nn)                            \
        acc[mm][4 + nn] = __builtin_amdgcn_mfma_i32_16x16x64_i8(                \
            af[P][mm], bfII[nn], acc[mm][4 + nn], 0, 0, 0);                     \
    __builtin_amdgcn_s_setprio(0);                                              \
    VMCNT(VM);                                                                  \
    BAR();                                                                      \
} while (0)

__global__ __launch_bounds__(512, 2) void gemm_i8_kernel(
        const int8_t* __restrict__ qa, const int8_t* __restrict__ qbT,
        const float* __restrict__ sL, const float* __restrict__ sR,
        float* __restrict__ out) {
    __shared__ __align__(16) int8_t lds[131072];

    const int t = threadIdx.x;
    const int wave = t >> 6;
    const int lane = t & 63;

    // 2D XCD partition (R7/R12-validated): each XCD owns 8mt x 8nt. Bijective.
    const int bid = blockIdx.x;
    const int xcd = bid & 7;
    const int idx = bid >> 3;                    // 0..63
    const int mt = (xcd >> 1) * 8 + (idx & 7);   // 0..31
    const int nt = (xcd & 1) * 8 + (idx >> 3);   // 0..15
    const int brow = mt * 256;
    const int bcol = nt * 256;

    const int wm = (wave >> 1) * 64;     // 4 M-groups of 64 rows
    const int wn = (wave & 1) * 128;     // 2 N-groups of 128 cols

    // fragment read byte-offsets (swizzled; 64B rows) — validated
    int aoff[4], boff[8];
#pragma unroll
    for (int m = 0; m < 4; ++m) {
        int row = wm + m * 16 + (lane & 15);
        aoff[m] = row * 64 + (((lane >> 4) ^ ((row >> 1) & 3)) * 16);
    }
#pragma unroll
    for (int n = 0; n < 8; ++n) {
        int row = wn + n * 16 + (lane & 15);
        boff[n] = 65536 + row * 64 + (((lane >> 4) ^ ((row >> 1) & 3)) * 16);
    }

    v4i acc[4][8];
#pragma unroll
    for (int m = 0; m < 4; ++m)
#pragma unroll
        for (int n = 0; n < 8; ++n) acc[m][n] = (v4i){0, 0, 0, 0};

    // staging: thread t covers bytes [t*16, t*16+16) of an 8KB half-tile;
    // source chunk pre-swizzled so linear LDS holds the swizzled layout.
    const int srow = t >> 2;                                  // 0..127
    const int lcA = (t & 3) ^ ((srow >> 1) & 3);
    const int8_t* gA0 = qa  + (size_t)(brow + srow) * K_DIM + lcA * 16;
    const int8_t* gB0 = qbT + (size_t)(bcol + srow) * K_DIM + lcA * 16;
    const int sdst = t * 16;

    v4i af[2][4], bfI[2][4], bfII[4];

    // prologue: stage tiles 0,1,2 (tile-monotone); drain T0,T1 for ALL waves
    // (VMCNT then BARRIER) BEFORE any LDS read -> no cross-wave race.
    STAGE_A(0, 0, 0); STAGE_A(1, 0, 0); STAGE_B(0, 0, 0); STAGE_B(1, 0, 0);
    STAGE_A(0, 1, 1); STAGE_A(1, 1, 1); STAGE_B(0, 1, 1); STAGE_B(1, 1, 1);
    STAGE_A(0, 2, 2); STAGE_A(1, 2, 2); STAGE_B(0, 2, 2); STAGE_B(1, 2, 2);
    VMCNT(4);
    BAR();
#pragma unroll
    for (int mm = 0; mm < 4; ++mm) af[0][mm] = RD_A(0, mm);
#pragma unroll
    for (int nn = 0; nn < 4; ++nn) bfI[0][nn] = RD_B(0, nn);

    for (int kt = 0; kt < 60; kt += 4) {
        TILE(kt + 0, 0, 0, 1, 4, 1);
        TILE(kt + 1, 1, 1, 1, 4, 1);
        TILE(kt + 2, 2, 0, 1, 4, 1);
        TILE(kt + 3, 3, 1, 1, 4, 1);
    }
    TILE(60, 0, 0, 1, 4, 1);   // stages T63; drains T62
    TILE(61, 1, 1, 0, 0, 1);   // drains T63 before barrier
    TILE(62, 2, 0, 0, 0, 1);
    TILE(63, 3, 1, 0, 0, 0);

    // Epilogue (validated): 16x16 C/D: col = lane&15, row = (lane>>4)*4 + reg
    const int r4 = (lane >> 4) * 4;
    const int cc = lane & 15;
#pragma unroll
    for (int m = 0; m < 4; ++m) {
        const int grow0 = brow + wm + m * 16 + r4;
        const float s0 = sL[grow0 + 0];
        const float s1 = sL[grow0 + 1];
        const float s2 = sL[grow0 + 2];
        const float s3 = sL[grow0 + 3];
#pragma unroll
        for (int n = 0; n < 8; ++n) {
            const int gcol = bcol + wn + n * 16 + cc;
            const float sc = sR[gcol];
            float* o = out + (size_t)grow0 * N_DIM + gcol;
            o[0 * N_DIM] = (float)acc[m][n][0] * s0 * sc;
            o[1 * N_DIM] = (float)acc[m][n][1] * s1 * sc;
            o[2 * N_DIM] = (float)acc[m][n][2] * s2 * sc;
            o[3 * N_DIM] = (float)acc[m][n][3] * s3 * sc;
        }
    }
}

// ---------------- launch ----------------
extern "C" void kernel_launch(void* const* d_in, const int* in_sizes, int n_in,
                              void* d_out, int out_size, void* d_ws, size_t ws_size,
                              hipStream_t stream) {
    const float* lhs = (const float*)d_in[0];
    const float* rhs = (const float*)d_in[1];
    float* out = (float*)d_out;

    uint8_t* ws = (uint8_t*)d_ws;
    int8_t* ql    = (int8_t*)ws;                               // 33,554,432 B
    int8_t* qbT   = (int8_t*)(ws + 33554432);                  // 16,777,216 B
    float* sL     = (float*)(ws + 50331648);                   // 32,768 B
    float* sR     = (float*)(ws + 50331648 + 32768);           // 16,384 B
    unsigned* bits = (unsigned*)(ws + 50331648 + 32768 + 16384); // 16,384 B

    hipMemsetAsync(bits, 0, N_DIM * sizeof(unsigned), stream);

    prep1_kernel<<<M_DIM + 1024, 256, 0, stream>>>(lhs, rhs, sL, bits, ql);
    quant_rhs_t_kernel<<<dim3(N_DIM / 64, K_DIM / 64), 256, 0, stream>>>(
        rhs, bits, sR, qbT);
    gemm_i8_kernel<<<dim3((M_DIM / 256) * (N_DIM / 256)), 512, 0, stream>>>(
        ql, qbT, sL, sR, out);
}